// Round 5
// baseline (287.176 us; speedup 1.0000x reference)
//
#include <hip/hip_runtime.h>
#include <hip/hip_bf16.h>
#include <cstdint>

using bf16 = __hip_bfloat16;
typedef __attribute__((ext_vector_type(8))) __bf16 bf16x8;
typedef __attribute__((ext_vector_type(4))) float f32x4;

#define MFMA16(a, b, c) __builtin_amdgcn_mfma_f32_16x16x32_bf16((a), (b), (c), 0, 0, 0)

#if __has_builtin(__builtin_amdgcn_exp2f)
__device__ __forceinline__ float fexp2(float x) { return __builtin_amdgcn_exp2f(x); }
#else
__device__ __forceinline__ float fexp2(float x) { return exp2f(x); }
#endif

// Async global->LDS 16B copy. LDS dest must be wave-uniform base + lane*16.
__device__ __forceinline__ void async16(void* lds_ptr, const void* gptr) {
  auto g = reinterpret_cast<__attribute__((address_space(1))) unsigned int*>(
      reinterpret_cast<uintptr_t>(gptr));
  auto l = reinterpret_cast<__attribute__((address_space(3))) unsigned int*>(
      static_cast<unsigned int>(reinterpret_cast<uintptr_t>(lds_ptr)));
  __builtin_amdgcn_global_load_lds(g, l, 16, 0, 0);
}

// ---------------------------------------------------------------- RMSNorm ----
__global__ __launch_bounds__(256) void rmsnorm_cast_k(
    const float* __restrict__ x, const float* __restrict__ sc, bf16* __restrict__ xn) {
  const int row = blockIdx.x, tid = threadIdx.x;
  const float4* xr = (const float4*)(x + (size_t)row * 2048);
  float4 a = xr[tid * 2], b = xr[tid * 2 + 1];
  float ss = a.x * a.x + a.y * a.y + a.z * a.z + a.w * a.w +
             b.x * b.x + b.y * b.y + b.z * b.z + b.w * b.w;
#pragma unroll
  for (int d = 1; d < 64; d <<= 1) ss += __shfl_xor(ss, d);
  __shared__ float sm[4];
  if ((tid & 63) == 0) sm[tid >> 6] = ss;
  __syncthreads();
  const float rinv = rsqrtf((sm[0] + sm[1] + sm[2] + sm[3]) * (1.0f / 2048.0f) + 1e-6f);
  const float4* sp = (const float4*)sc;
  float4 s0 = sp[tid * 2], s1 = sp[tid * 2 + 1];
  union { bf16 h[8]; bf16x8 v; } o;
  o.h[0] = __float2bfloat16(a.x * rinv * s0.x);
  o.h[1] = __float2bfloat16(a.y * rinv * s0.y);
  o.h[2] = __float2bfloat16(a.z * rinv * s0.z);
  o.h[3] = __float2bfloat16(a.w * rinv * s0.w);
  o.h[4] = __float2bfloat16(b.x * rinv * s1.x);
  o.h[5] = __float2bfloat16(b.y * rinv * s1.y);
  o.h[6] = __float2bfloat16(b.z * rinv * s1.z);
  o.h[7] = __float2bfloat16(b.w * rinv * s1.w);
  *(bf16x8*)(xn + (size_t)row * 2048 + tid * 8) = o.v;
}

// ------------------------------------------------- weight transpose + cast ----
__global__ void transpose_cast_k(const float* __restrict__ W, bf16* __restrict__ Wt,
                                 int N, int row_off) {
  __shared__ float t[32][33];
  const int n0 = blockIdx.x * 32, k0 = blockIdx.y * 32;
  const int tx = threadIdx.x, ty = threadIdx.y;
#pragma unroll
  for (int i = 0; i < 4; ++i)
    t[ty + 8 * i][tx] = W[(size_t)(k0 + ty + 8 * i) * N + n0 + tx];
  __syncthreads();
#pragma unroll
  for (int i = 0; i < 4; ++i)
    Wt[(size_t)(row_off + n0 + ty + 8 * i) * 2048 + k0 + tx] =
        __float2bfloat16(t[tx][ty + 8 * i]);
}

// V slice of QKV [4096][3072] (cols 2560..3071) -> Vt bf16 [16][128][1024]
__global__ void transpose_v_k(const bf16* __restrict__ qkv, bf16* __restrict__ vtb) {
  __shared__ bf16 t[32][33];
  const int bh = blockIdx.z, b = bh >> 2, g = bh & 3;
  const int s0 = blockIdx.x * 32, d0 = blockIdx.y * 32;
  const int tx = threadIdx.x, ty = threadIdx.y;
#pragma unroll
  for (int i = 0; i < 4; ++i)
    t[ty + 8 * i][tx] =
        qkv[(size_t)(b * 1024 + s0 + ty + 8 * i) * 3072 + 2560 + g * 128 + d0 + tx];
  __syncthreads();
#pragma unroll
  for (int i = 0; i < 4; ++i)
    vtb[((size_t)bh * 128 + d0 + ty + 8 * i) * 1024 + s0 + tx] = t[tx][ty + 8 * i];
}

__global__ void concat_bias_k(const float* __restrict__ bq, const float* __restrict__ bk,
                              const float* __restrict__ bv, const float* __restrict__ b1,
                              float* __restrict__ o) {
  const int i = blockIdx.x * 256 + threadIdx.x;
  if (i < 2048) o[i] = bq[i];
  else if (i < 2560) o[i] = bk[i - 2048];
  else if (i < 3072) o[i] = bv[i - 2560];
  else o[i] = b1[i - 3072];
}

// --------------------------- ring GEMM with register read-ahead (T3/T4) ------
// C[M][N] = A[M][K] @ Bt[N][K]^T. Tile 128x128, 4 waves, BK-half = 32.
// LDS ring of 4 half-slots per matrix (A 4x8KB @0, B 4x8KB @32KB) = 64KB.
// Phase h: ds_read frags(slot h+1) into the OTHER reg set || stage S(h+3) ||
// vmcnt(4) || MFMA(frags h) || lgkm(0) || barrier.  Invariant at phase-h entry:
// slots h,h+1 valid, S(h+2) (4 loads/thread) may be outstanding.
// Slot reuse race-free: reads of slot s drain (lgkm0+barrier) 2 phases before
// the S(s+4) stage that overwrites it.
#define PH_READ(AF, BF, SLOT)                                                      \
  {                                                                                \
    const int sa = (SLOT)*8192, sb = 32768 + sa;                                   \
    _Pragma("unroll") for (int mi = 0; mi < 4; ++mi) {                             \
      const int R = (w >> 1) * 64 + mi * 16 + lo;                                  \
      AF[mi] = *(const bf16x8*)(lds + sa + R * 64 + ((hi ^ ((R >> 1) & 3)) << 4)); \
    }                                                                              \
    _Pragma("unroll") for (int nj = 0; nj < 4; ++nj) {                             \
      const int S = (w & 1) * 64 + nj * 16 + lo;                                   \
      BF[nj] = *(const bf16x8*)(lds + sb + S * 64 + ((hi ^ ((S >> 1) & 3)) << 4)); \
    }                                                                              \
  }

#define PH_MFMA(AF, BF)                                                            \
  __builtin_amdgcn_s_setprio(1);                                                   \
  _Pragma("unroll") for (int mi = 0; mi < 4; ++mi)                                 \
    _Pragma("unroll") for (int nj = 0; nj < 4; ++nj)                               \
      acc[mi][nj] = MFMA16(AF[mi], BF[nj], acc[mi][nj]);                           \
  __builtin_amdgcn_s_setprio(0);

#define PH_TAIL_SYNC                                                               \
  asm volatile("s_waitcnt lgkmcnt(0)" ::: "memory");                               \
  __builtin_amdgcn_sched_barrier(0);                                               \
  __builtin_amdgcn_s_barrier();                                                    \
  asm volatile("" ::: "memory");

template <int EPI>
__global__ __launch_bounds__(256, 2) void gemm_r(
    const bf16* __restrict__ A, const bf16* __restrict__ Bt,
    const float* __restrict__ bias, const float* __restrict__ res,
    void* __restrict__ out0, void* __restrict__ out1, int K) {
  __shared__ __align__(16) unsigned char lds[65536];
  const int tid = threadIdx.x, lane = tid & 63, w = tid >> 6;
  const int hi = lane >> 4, lo = lane & 15;
  const int brow = blockIdx.x * 128, bcol = blockIdx.y * 128;
  const int nt = K >> 6;  // number of 64-K tiles; total phases H = 2*nt

  // staging coords: half-slot is [128 rows][64B]; thread covers bytes o0, o1.
  const int o0 = tid * 16, o1 = o0 + 4096;
  const int r0 = o0 >> 6, c0 = ((((o0 >> 4) & 3) ^ ((r0 >> 1) & 3)) << 3);
  const int r1 = o1 >> 6, c1 = ((((o1 >> 4) & 3) ^ ((r1 >> 1) & 3)) << 3);
  const bf16* gA0 = A + (size_t)(brow + r0) * K + c0;
  const bf16* gA1 = A + (size_t)(brow + r1) * K + c1;
  const bf16* gB0 = Bt + (size_t)(bcol + r0) * K + c0;
  const bf16* gB1 = Bt + (size_t)(bcol + r1) * K + c1;

  auto stg = [&](int h) {
    const int s = (h & 3) * 8192;
    const int kb = h * 32;
    async16(lds + s + o0, gA0 + kb);
    async16(lds + s + o1, gA1 + kb);
    async16(lds + 32768 + s + o0, gB0 + kb);
    async16(lds + 32768 + s + o1, gB1 + kb);
  };

  stg(0); stg(1); stg(2);  // 12 loads/thread in flight
  asm volatile("s_waitcnt vmcnt(4)" ::: "memory");  // slots 0,1 landed
  __builtin_amdgcn_sched_barrier(0);
  __builtin_amdgcn_s_barrier();
  asm volatile("" ::: "memory");

  f32x4 acc[4][4] = {};
  bf16x8 afA[4], bfA[4], afB[4], bfB[4];
  PH_READ(afA, bfA, 0);

  // main pairs: phases 0 .. 2*nt-5  (each iter = 2 phases)
  for (int t = 0; t < nt - 2; ++t) {
    const int h = 2 * t;
    // phase h (cur = A)
    PH_READ(afB, bfB, (h + 1) & 3);
    stg(h + 3);
    asm volatile("s_waitcnt vmcnt(4)" ::: "memory");
    __builtin_amdgcn_sched_barrier(0);
    PH_MFMA(afA, bfA);
    PH_TAIL_SYNC;
    // phase h+1 (cur = B)
    PH_READ(afA, bfA, (h + 2) & 3);
    stg(h + 4);
    asm volatile("s_waitcnt vmcnt(4)" ::: "memory");
    __builtin_amdgcn_sched_barrier(0);
    PH_MFMA(afB, bfB);
    PH_TAIL_SYNC;
  }
  {
    const int ht = 2 * nt - 4;
    // phase ht (cur = A): last stage
    PH_READ(afB, bfB, (ht + 1) & 3);
    stg(ht + 3);
    asm volatile("s_waitcnt vmcnt(4)" ::: "memory");
    __builtin_amdgcn_sched_barrier(0);
    PH_MFMA(afA, bfA);
    PH_TAIL_SYNC;
    // phase ht+1 (cur = B): drain all loads
    PH_READ(afA, bfA, (ht + 2) & 3);
    asm volatile("s_waitcnt vmcnt(0)" ::: "memory");
    __builtin_amdgcn_sched_barrier(0);
    PH_MFMA(afB, bfB);
    PH_TAIL_SYNC;
    // phase ht+2 (cur = A)
    PH_READ(afB, bfB, (ht + 3) & 3);
    PH_MFMA(afA, bfA);
    // phase ht+3 (cur = B) — dataflow orders the reads before these MFMAs
    PH_MFMA(afB, bfB);
  }

#pragma unroll
  for (int nj = 0; nj < 4; ++nj) {
    const int col = bcol + (w & 1) * 64 + nj * 16 + lo;
    const float bs = bias[col];
#pragma unroll
    for (int mi = 0; mi < 4; ++mi) {
      const int row0 = brow + (w >> 1) * 64 + mi * 16 + hi * 4;
#pragma unroll
      for (int r = 0; r < 4; ++r) {
        float v = acc[mi][nj][r] + bs;
        const int row = row0 + r;
        if (EPI == 0) {
          if (bcol < 3072) {
            ((bf16*)out0)[(size_t)row * 3072 + col] = __float2bfloat16(v);
          } else {
            const float sg = 1.0f / (1.0f + __expf(-v));
            v = v * sg * v;
            ((bf16*)out1)[(size_t)row * 2048 + (col - 3072)] = __float2bfloat16(v);
          }
        } else {
          v += res[(size_t)row * 2048 + col];
          ((float*)out0)[(size_t)row * 2048 + col] = v;
        }
      }
    }
  }
}

// --------------------------------------------------------------- attention ----
__global__ __launch_bounds__(256, 4) void attn_fwd(
    const bf16* __restrict__ qkv, const bf16* __restrict__ vtb, bf16* __restrict__ out) {
  __shared__ __align__(16) unsigned char lds[40960];
  unsigned char* Ks = lds;
  unsigned char* Vs = lds + 16384;
  unsigned char* Ps = lds + 32768;
  const int tid = threadIdx.x, lane = tid & 63, w = tid >> 6;
  const int hi = lane >> 4, lo = lane & 15;
  const int qt = blockIdx.x, bh = blockIdx.y;
  const int b = bh >> 4, h = bh & 15, g = h >> 2;
  const size_t tok0 = (size_t)b * 1024;
  const int q0 = qt * 64;

  bf16x8 qf[4];
  {
    const bf16* qp = qkv + (tok0 + q0 + w * 16 + lo) * 3072 + h * 128 + hi * 8;
#pragma unroll
    for (int kc = 0; kc < 4; ++kc) qf[kc] = *(const bf16x8*)(qp + kc * 32);
  }

  float m2 = -1e30f, lsum = 0.f;
  f32x4 oacc[8] = {};
  const float c2 = 0.08838834764831845f * 1.44269504088896f;

  const int o = tid * 16;
  const bf16* kbase = qkv + tok0 * 3072 + 2048 + g * 128;
  const bf16* vbase = vtb + (size_t)(b * 4 + g) * 128 * 1024;
  unsigned char* Pw = Ps + w * 2048;

  for (int t = 0; t < 16; ++t) {
    const int kb = t * 64;
#pragma unroll
    for (int rd = 0; rd < 4; ++rd) {
      const int oo = o + rd * 4096;
      const int rK = oo >> 8, cK = ((oo >> 4) & 15) ^ (rK & 15);
      const int rV = oo >> 7, cV = ((oo >> 4) & 7) ^ (rV & 7);
      async16(Ks + oo, kbase + (size_t)(kb + rK) * 3072 + cK * 8);
      async16(Vs + oo, vbase + (size_t)rV * 1024 + kb + cV * 8);
    }
    __syncthreads();

    f32x4 sc[4] = {};
#pragma unroll
    for (int kc = 0; kc < 4; ++kc) {
#pragma unroll
      for (int kg = 0; kg < 4; ++kg) {
        const int row = kg * 16 + lo;
        bf16x8 kf = *(const bf16x8*)(Ks + row * 256 + ((((kc << 2) + hi) ^ (row & 15)) << 4));
        sc[kg] = MFMA16(kf, qf[kc], sc[kg]);
      }
    }

    float mx = sc[0][0];
#pragma unroll
    for (int kg = 0; kg < 4; ++kg)
#pragma unroll
      for (int r = 0; r < 4; ++r) mx = fmaxf(mx, sc[kg][r]);
    mx = fmaxf(mx, __shfl_xor(mx, 16));
    mx = fmaxf(mx, __shfl_xor(mx, 32));
    mx *= c2;
    const float mn = fmaxf(m2, mx);
    const float corr = fexp2(m2 - mn);
    m2 = mn;

    float rs = 0.f;
#pragma unroll
    for (int kg = 0; kg < 4; ++kg) {
      union { bf16 hh[4]; uint2 v; } pk;
#pragma unroll
      for (int r = 0; r < 4; ++r) {
        const float p = fexp2(sc[kg][r] * c2 - mn);
        rs += p;
        pk.hh[r] = __float2bfloat16(p);
      }
      *(uint2*)(Pw + lo * 128 + ((((kg << 1) + (hi >> 1)) ^ (lo & 7)) << 4) +
                ((hi & 1) << 3)) = pk.v;
    }
    rs += __shfl_xor(rs, 16);
    rs += __shfl_xor(rs, 32);
    lsum = lsum * corr + rs;

    float corr_r[4];
#pragma unroll
    for (int r = 0; r < 4; ++r) corr_r[r] = __shfl(corr, hi * 4 + r);
#pragma unroll
    for (int dg = 0; dg < 8; ++dg)
#pragma unroll
      for (int r = 0; r < 4; ++r) oacc[dg][r] *= corr_r[r];

    asm volatile("s_waitcnt lgkmcnt(0)" ::: "memory");

    bf16x8 pf[2];
#pragma unroll
    for (int kc = 0; kc < 2; ++kc)
      pf[kc] = *(const bf16x8*)(Pw + lo * 128 + ((((kc << 2) + hi) ^ (lo & 7)) << 4));
#pragma unroll
    for (int dg = 0; dg < 8; ++dg) {
#pragma unroll
      for (int kc = 0; kc < 2; ++kc) {
        const int vrow = dg * 16 + lo;
        bf16x8 vf = *(const bf16x8*)(Vs + vrow * 128 + ((((kc << 2) + hi) ^ (vrow & 7)) << 4));
        oacc[dg] = MFMA16(pf[kc], vf, oacc[dg]);
      }
    }
    __syncthreads();
  }

  const float linv = 1.0f / lsum;
  float lr[4];
#pragma unroll
  for (int r = 0; r < 4; ++r) lr[r] = __shfl(linv, hi * 4 + r);
  bf16* op = out + (tok0 + q0 + w * 16 + hi * 4) * 2048 + h * 128 + lo;
#pragma unroll
  for (int dg = 0; dg < 8; ++dg)
#pragma unroll
    for (int r = 0; r < 4; ++r)
      op[(size_t)r * 2048 + dg * 16] = __float2bfloat16(oacc[dg][r] * lr[r]);
}

// ------------------------------------------------------------------ launch ----
extern "C" void kernel_launch(void* const* d_in, const int* in_sizes, int n_in,
                              void* d_out, int out_size, void* d_ws, size_t ws_size,
                              hipStream_t stream) {
  (void)in_sizes; (void)n_in; (void)out_size; (void)ws_size;
  const float* x  = (const float*)d_in[0];
  const float* s1 = (const float*)d_in[1];
  const float* Wq = (const float*)d_in[2];
  const float* bq = (const float*)d_in[3];
  const float* Wk = (const float*)d_in[4];
  const float* bk = (const float*)d_in[5];
  const float* Wv = (const float*)d_in[6];
  const float* bv = (const float*)d_in[7];
  const float* Wo = (const float*)d_in[8];
  const float* bo = (const float*)d_in[9];
  const float* W1 = (const float*)d_in[10];
  const float* b1 = (const float*)d_in[11];
  const float* W2 = (const float*)d_in[12];
  const float* b2 = (const float*)d_in[13];
  float* outp = (float*)d_out;

  char* ws = (char*)d_ws;
  bf16*  xn    = (bf16*)(ws + 0);            // 16.78 MB [4096][2048]; dead after gemm_r<0>
  bf16*  vtb   = (bf16*)(ws + 0);            // 4.19 MB, aliases dead xn
  bf16*  wcatT = (bf16*)(ws + 16777216);     // 20.97 MB [5120][2048]; dead after gemm_r<0>
  bf16*  attnb = (bf16*)(ws + 16777216);     // 16.78 MB, aliases dead wcatT
  float* bcat  = (float*)(ws + 37748736);    // 20 KB
  bf16*  woT   = (bf16*)(ws + 37769216);     // 8.39 MB
  bf16*  w2T   = (bf16*)(ws + 46157824);     // 8.39 MB
  bf16*  qkvb  = (bf16*)(ws + 54546432);     // 25.17 MB [4096][3072]
  bf16*  gbuf  = (bf16*)(ws + 79712256);     // 16.78 MB [4096][2048]
  float* x1    = outp;                       // residual mid lives in d_out

  const dim3 b32x8(32, 8);
  rmsnorm_cast_k<<<dim3(4096), dim3(256), 0, stream>>>(x, s1, xn);
  concat_bias_k<<<dim3(20), dim3(256), 0, stream>>>(bq, bk, bv, b1, bcat);
  transpose_cast_k<<<dim3(64, 64), b32x8, 0, stream>>>(Wq, wcatT, 2048, 0);
  transpose_cast_k<<<dim3(16, 64), b32x8, 0, stream>>>(Wk, wcatT, 512, 2048);
  transpose_cast_k<<<dim3(16, 64), b32x8, 0, stream>>>(Wv, wcatT, 512, 2560);
  transpose_cast_k<<<dim3(64, 64), b32x8, 0, stream>>>(W1, wcatT, 2048, 3072);
  transpose_cast_k<<<dim3(64, 64), b32x8, 0, stream>>>(Wo, woT, 2048, 0);
  transpose_cast_k<<<dim3(64, 64), b32x8, 0, stream>>>(W2, w2T, 2048, 0);
  // merged QKV + W1 projection: [4096,2048] x [2048,5120], 1280 blocks
  gemm_r<0><<<dim3(32, 40), dim3(256), 0, stream>>>(xn, wcatT, bcat, (const float*)nullptr,
                                                    (void*)qkvb, (void*)gbuf, 2048);
  transpose_v_k<<<dim3(32, 4, 16), b32x8, 0, stream>>>(qkvb, vtb);
  attn_fwd<<<dim3(16, 64), dim3(256), 0, stream>>>(qkvb, vtb, attnb);
  // x1 = x + attn @ Wo + bo
  gemm_r<1><<<dim3(32, 16), dim3(256), 0, stream>>>(attnb, woT, bo, x, (void*)x1,
                                                    (void*)nullptr, 2048);
  // out = x1 + g @ W2 + b2
  gemm_r<1><<<dim3(32, 16), dim3(256), 0, stream>>>(gbuf, w2T, b2, x1, (void*)outp,
                                                    (void*)nullptr, 2048);
}

// Round 6
// 262.006 us; speedup vs baseline: 1.0961x; 1.0961x over previous
//
#include <hip/hip_runtime.h>
#include <hip/hip_bf16.h>
#include <cstdint>

using bf16 = __hip_bfloat16;
typedef __attribute__((ext_vector_type(8))) __bf16 bf16x8;
typedef __attribute__((ext_vector_type(4))) float f32x4;

#define MFMA16(a, b, c) __builtin_amdgcn_mfma_f32_16x16x32_bf16((a), (b), (c), 0, 0, 0)

#if __has_builtin(__builtin_amdgcn_exp2f)
__device__ __forceinline__ float fexp2(float x) { return __builtin_amdgcn_exp2f(x); }
#else
__device__ __forceinline__ float fexp2(float x) { return exp2f(x); }
#endif

// Async global->LDS 16B copy. LDS dest must be wave-uniform base + lane*16.
__device__ __forceinline__ void async16(void* lds_ptr, const void* gptr) {
  auto g = reinterpret_cast<__attribute__((address_space(1))) unsigned int*>(
      reinterpret_cast<uintptr_t>(gptr));
  auto l = reinterpret_cast<__attribute__((address_space(3))) unsigned int*>(
      static_cast<unsigned int>(reinterpret_cast<uintptr_t>(lds_ptr)));
  __builtin_amdgcn_global_load_lds(g, l, 16, 0, 0);
}

// ---------------------------------------------------------------- RMSNorm ----
__global__ __launch_bounds__(256) void rmsnorm_cast_k(
    const float* __restrict__ x, const float* __restrict__ sc, bf16* __restrict__ xn) {
  const int row = blockIdx.x, tid = threadIdx.x;
  const float4* xr = (const float4*)(x + (size_t)row * 2048);
  float4 a = xr[tid * 2], b = xr[tid * 2 + 1];
  float ss = a.x * a.x + a.y * a.y + a.z * a.z + a.w * a.w +
             b.x * b.x + b.y * b.y + b.z * b.z + b.w * b.w;
#pragma unroll
  for (int d = 1; d < 64; d <<= 1) ss += __shfl_xor(ss, d);
  __shared__ float sm[4];
  if ((tid & 63) == 0) sm[tid >> 6] = ss;
  __syncthreads();
  const float rinv = rsqrtf((sm[0] + sm[1] + sm[2] + sm[3]) * (1.0f / 2048.0f) + 1e-6f);
  const float4* sp = (const float4*)sc;
  float4 s0 = sp[tid * 2], s1 = sp[tid * 2 + 1];
  union { bf16 h[8]; bf16x8 v; } o;
  o.h[0] = __float2bfloat16(a.x * rinv * s0.x);
  o.h[1] = __float2bfloat16(a.y * rinv * s0.y);
  o.h[2] = __float2bfloat16(a.z * rinv * s0.z);
  o.h[3] = __float2bfloat16(a.w * rinv * s0.w);
  o.h[4] = __float2bfloat16(b.x * rinv * s1.x);
  o.h[5] = __float2bfloat16(b.y * rinv * s1.y);
  o.h[6] = __float2bfloat16(b.z * rinv * s1.z);
  o.h[7] = __float2bfloat16(b.w * rinv * s1.w);
  *(bf16x8*)(xn + (size_t)row * 2048 + tid * 8) = o.v;
}

// ------------------------------------------------- weight transpose + cast ----
// W f32 [2048][N] -> Wt[(row_off + n) * ldt + k_off + k] = bf16(W[k][n])
__global__ void transpose_cast_k(const float* __restrict__ W, bf16* __restrict__ Wt,
                                 int N, int ldt, int row_off, int k_off) {
  __shared__ float t[32][33];
  const int n0 = blockIdx.x * 32, k0 = blockIdx.y * 32;
  const int tx = threadIdx.x, ty = threadIdx.y;
#pragma unroll
  for (int i = 0; i < 4; ++i)
    t[ty + 8 * i][tx] = W[(size_t)(k0 + ty + 8 * i) * N + n0 + tx];
  __syncthreads();
#pragma unroll
  for (int i = 0; i < 4; ++i)
    Wt[(size_t)(row_off + n0 + ty + 8 * i) * ldt + k_off + k0 + tx] =
        __float2bfloat16(t[tx][ty + 8 * i]);
}

// V slice of QKV [4096][3072] (cols 2560..3071) -> Vt bf16 [16][128][1024]
__global__ void transpose_v_k(const bf16* __restrict__ qkv, bf16* __restrict__ vtb) {
  __shared__ bf16 t[32][33];
  const int bh = blockIdx.z, b = bh >> 2, g = bh & 3;
  const int s0 = blockIdx.x * 32, d0 = blockIdx.y * 32;
  const int tx = threadIdx.x, ty = threadIdx.y;
#pragma unroll
  for (int i = 0; i < 4; ++i)
    t[ty + 8 * i][tx] =
        qkv[(size_t)(b * 1024 + s0 + ty + 8 * i) * 3072 + 2560 + g * 128 + d0 + tx];
  __syncthreads();
#pragma unroll
  for (int i = 0; i < 4; ++i)
    vtb[((size_t)bh * 128 + d0 + ty + 8 * i) * 1024 + s0 + tx] = t[tx][ty + 8 * i];
}

// bcat layout: [0..3071]=bq|bk|bv, [3072..5119]=b1, [5120..7167]=bo+b2
__global__ void concat_bias_k(const float* __restrict__ bq, const float* __restrict__ bk,
                              const float* __restrict__ bv, const float* __restrict__ b1,
                              const float* __restrict__ bo, const float* __restrict__ b2,
                              float* __restrict__ o) {
  const int i = blockIdx.x * 256 + threadIdx.x;
  if (i < 2048) o[i] = bq[i];
  else if (i < 2560) o[i] = bk[i - 2048];
  else if (i < 3072) o[i] = bv[i - 2560];
  else if (i < 5120) o[i] = b1[i - 3072];
  else o[i] = bo[i - 5120] + b2[i - 5120];
}

// --------------------- 8-wave ring GEMM, fat per-wave panels (m201-style) ----
// C[M][N] = A[M][K] @ Bt[N][K]^T. Block = (WM*MI*16) x (WN*NJ*16), 512 thr,
// 8 waves each owning a (MI*16) x (NJ*16) panel. K processed in 32-wide slots,
// LDS ring of 4 slots per matrix. Per slot: 2 phases
//   {ds_read fragments ; stage slot h+3 ; barrier ; lgkm(0) ; setprio MFMA ; barrier}
// with one counted vmcnt (2 slots in flight, FIFO-oldest semantics) per slot.
// A is always ld 2048. EPI==1 reads A for k<2048 and A2 for k>=2048 (K=4096).
#define BARRIER() \
  { asm volatile("" ::: "memory"); __builtin_amdgcn_s_barrier(); asm volatile("" ::: "memory"); }
#define LGKM0() \
  { asm volatile("s_waitcnt lgkmcnt(0)" ::: "memory"); __builtin_amdgcn_sched_barrier(0); }
#define VM_MAIN                                                          \
  { if constexpr (LPS == 4) { asm volatile("s_waitcnt vmcnt(8)" ::: "memory"); } \
    else { asm volatile("s_waitcnt vmcnt(6)" ::: "memory"); }            \
    __builtin_amdgcn_sched_barrier(0); }
#define VM_ONE                                                           \
  { if constexpr (LPS == 4) { asm volatile("s_waitcnt vmcnt(4)" ::: "memory"); } \
    else { asm volatile("s_waitcnt vmcnt(3)" ::: "memory"); }            \
    __builtin_amdgcn_sched_barrier(0); }
#define VM_ZERO \
  { asm volatile("s_waitcnt vmcnt(0)" ::: "memory"); __builtin_amdgcn_sched_barrier(0); }

#define READ_AF(MILO)                                                              \
  { unsigned char* ab_ = lds + (h_ & 3) * SLOTA;                                   \
    _Pragma("unroll") for (int i_ = 0; i_ < MI / 2; ++i_) {                        \
      const int R_ = arow0 + ((MILO) + i_) * 16;                                   \
      af[i_] = *(const bf16x8*)(ab_ + R_ * 64 + ((hi ^ ((R_ >> 1) & 3)) << 4)); } }

#define READ_BF()                                                                  \
  { unsigned char* bb_ = lds + 4 * SLOTA + (h_ & 3) * SLOTB;                       \
    _Pragma("unroll") for (int j_ = 0; j_ < NJ; ++j_) {                            \
      const int S_ = bcol0 + j_ * 16;                                              \
      bf[j_] = *(const bf16x8*)(bb_ + S_ * 64 + ((hi ^ ((S_ >> 1) & 3)) << 4)); } }

#define MFMA_HALF(MILO)                                                            \
  __builtin_amdgcn_s_setprio(1);                                                   \
  _Pragma("unroll") for (int i_ = 0; i_ < MI / 2; ++i_)                            \
    _Pragma("unroll") for (int j_ = 0; j_ < NJ; ++j_)                              \
      acc[(MILO) + i_][j_] = MFMA16(af[i_], bf[j_], acc[(MILO) + i_][j_]);         \
  __builtin_amdgcn_s_setprio(0);

#define GSLOT(H, DOSTG, VMSTMT)                                                    \
  { const int h_ = (H);                                                            \
    READ_AF(0); READ_BF();                                                         \
    if (DOSTG) stgA(h_ + 3);                                                       \
    BARRIER(); LGKM0();                                                            \
    MFMA_HALF(0);                                                                  \
    BARRIER();                                                                     \
    READ_AF(MI / 2);                                                               \
    if (DOSTG) stgB(h_ + 3);                                                       \
    VMSTMT;                                                                        \
    BARRIER(); LGKM0();                                                            \
    MFMA_HALF(MI / 2);                                                             \
    BARRIER(); }

template <int MI, int NJ, int WM, int WN, int EPI>
__global__ __launch_bounds__(512, 1) void gemm8(
    const bf16* __restrict__ A, const bf16* __restrict__ A2,
    const bf16* __restrict__ Bt, const float* __restrict__ bias,
    const float* __restrict__ res, void* __restrict__ out0,
    void* __restrict__ out1, int K) {
  constexpr int BM = WM * MI * 16;
  constexpr int BN = WN * NJ * 16;
  constexpr int SLOTA = BM * 64;   // bytes per A 32-K slot
  constexpr int SLOTB = BN * 64;
  constexpr int NSWA = SLOTA / 8192;
  constexpr int NSWB = SLOTB / 8192;
  constexpr int FRACB = SLOTB % 8192;  // partial sweep (first FRACB/16 threads)
  constexpr int LPS = NSWA + NSWB;     // ledger loads/slot (min over waves)
  extern __shared__ unsigned char lds[];

  const int tid = threadIdx.x, lane = tid & 63, w = tid >> 6;
  const int wr = w / WN, wc = w % WN;
  const int hi = lane >> 4, lo = lane & 15;

  // XCD-aware swizzle over the 16x16 grid (256 blocks, divisible by 8)
  const int lid = blockIdx.y * 16 + blockIdx.x;
  const int swz = (lid & 7) * 32 + (lid >> 3);
  const int brow = (swz & 15) * BM;
  const int bcol = (swz >> 4) * BN;

  const int NS = K >> 5;

  // staging source precompute (A ld fixed 2048; B ld = K)
  size_t offA[NSWA];
#pragma unroll
  for (int i = 0; i < NSWA; ++i) {
    const int o = i * 8192 + tid * 16;
    const int r = o >> 6;
    const int c = ((((o >> 4) & 3) ^ ((r >> 1) & 3)) << 3);
    offA[i] = (size_t)(brow + r) * 2048 + c;
  }
  const bf16* srcB[NSWB + (FRACB ? 1 : 0)];
#pragma unroll
  for (int i = 0; i < NSWB + (FRACB ? 1 : 0); ++i) {
    const int o = i * 8192 + tid * 16;
    const int r = o >> 6;
    const int c = ((((o >> 4) & 3) ^ ((r >> 1) & 3)) << 3);
    srcB[i] = Bt + (size_t)(bcol + r) * K + c;
  }

  auto stgA = [&](int h) {
    unsigned char* ab = lds + (h & 3) * SLOTA;
    const int kb = h * 32;
    const bf16* base;
    int ko;
    if constexpr (EPI == 1) { base = (kb < 2048) ? A : A2; ko = kb & 2047; }
    else { base = A; ko = kb; }
#pragma unroll
    for (int i = 0; i < NSWA; ++i)
      async16(ab + i * 8192 + tid * 16, base + offA[i] + ko);
  };
  auto stgB = [&](int h) {
    unsigned char* bb = lds + 4 * SLOTA + (h & 3) * SLOTB;
    const int kb = h * 32;
#pragma unroll
    for (int i = 0; i < NSWB; ++i)
      async16(bb + i * 8192 + tid * 16, srcB[i] + kb);
    if constexpr (FRACB != 0) {
      if (tid < FRACB / 16)
        async16(bb + NSWB * 8192 + tid * 16, srcB[NSWB] + kb);
    }
  };

  const int arow0 = wr * (MI * 16) + lo;
  const int bcol0 = wc * (NJ * 16) + lo;

  // prologue: 3 slots in flight; vmcnt leaves 2 -> slot 0 landed (FIFO-oldest)
  stgA(0); stgB(0); stgA(1); stgB(1); stgA(2); stgB(2);
  VM_MAIN;
  BARRIER();

  f32x4 acc[MI][NJ] = {};
  bf16x8 af[MI / 2], bf[NJ];

  for (int h = 0; h < NS - 3; ++h) { GSLOT(h, true, VM_MAIN); }
  GSLOT(NS - 3, false, VM_ONE);
  GSLOT(NS - 2, false, VM_ZERO);
  GSLOT(NS - 1, false, (void)0);

#pragma unroll
  for (int mi = 0; mi < MI; ++mi) {
    const int row = brow + wr * (MI * 16) + mi * 16 + hi * 4;
#pragma unroll
    for (int nj = 0; nj < NJ; ++nj) {
      const int col = bcol + wc * (NJ * 16) + nj * 16 + lo;
      const float bs = bias[col];
#pragma unroll
      for (int r = 0; r < 4; ++r) {
        float v = acc[mi][nj][r] + bs;
        if constexpr (EPI == 0) {
          if (col < 3072) {
            ((bf16*)out0)[(size_t)(row + r) * 3072 + col] = __float2bfloat16(v);
          } else {
            const float sg = 1.0f / (1.0f + __expf(-v));
            ((bf16*)out1)[(size_t)(row + r) * 2048 + (col - 3072)] =
                __float2bfloat16(v * sg * v);
          }
        } else {
          v += res[(size_t)(row + r) * 2048 + col];
          ((float*)out0)[(size_t)(row + r) * 2048 + col] = v;
        }
      }
    }
  }
}

// --------------------------------------------------------------- attention ----
__global__ __launch_bounds__(256, 4) void attn_fwd(
    const bf16* __restrict__ qkv, const bf16* __restrict__ vtb, bf16* __restrict__ out) {
  __shared__ __align__(16) unsigned char alds[40960];
  unsigned char* Ks = alds;
  unsigned char* Vs = alds + 16384;
  unsigned char* Ps = alds + 32768;
  const int tid = threadIdx.x, lane = tid & 63, w = tid >> 6;
  const int hi = lane >> 4, lo = lane & 15;
  const int qt = blockIdx.x, bh = blockIdx.y;
  const int b = bh >> 4, h = bh & 15, g = h >> 2;
  const size_t tok0 = (size_t)b * 1024;
  const int q0 = qt * 64;

  bf16x8 qf[4];
  {
    const bf16* qp = qkv + (tok0 + q0 + w * 16 + lo) * 3072 + h * 128 + hi * 8;
#pragma unroll
    for (int kc = 0; kc < 4; ++kc) qf[kc] = *(const bf16x8*)(qp + kc * 32);
  }

  float m2 = -1e30f, lsum = 0.f;
  f32x4 oacc[8] = {};
  const float c2 = 0.08838834764831845f * 1.44269504088896f;

  const int o = tid * 16;
  const bf16* kbase = qkv + tok0 * 3072 + 2048 + g * 128;
  const bf16* vbase = vtb + (size_t)(b * 4 + g) * 128 * 1024;
  unsigned char* Pw = Ps + w * 2048;

  for (int t = 0; t < 16; ++t) {
    const int kb = t * 64;
#pragma unroll
    for (int rd = 0; rd < 4; ++rd) {
      const int oo = o + rd * 4096;
      const int rK = oo >> 8, cK = ((oo >> 4) & 15) ^ (rK & 15);
      const int rV = oo >> 7, cV = ((oo >> 4) & 7) ^ (rV & 7);
      async16(Ks + oo, kbase + (size_t)(kb + rK) * 3072 + cK * 8);
      async16(Vs + oo, vbase + (size_t)rV * 1024 + kb + cV * 8);
    }
    __syncthreads();

    f32x4 sc[4] = {};
#pragma unroll
    for (int kc = 0; kc < 4; ++kc) {
#pragma unroll
      for (int kg = 0; kg < 4; ++kg) {
        const int row = kg * 16 + lo;
        bf16x8 kf = *(const bf16x8*)(Ks + row * 256 + ((((kc << 2) + hi) ^ (row & 15)) << 4));
        sc[kg] = MFMA16(kf, qf[kc], sc[kg]);
      }
    }

    float mx = sc[0][0];
#pragma unroll
    for (int kg = 0; kg < 4; ++kg)
#pragma unroll
      for (int r = 0; r < 4; ++r) mx = fmaxf(mx, sc[kg][r]);
    mx = fmaxf(mx, __shfl_xor(mx, 16));
    mx = fmaxf(mx, __shfl_xor(mx, 32));
    mx *= c2;
    const float mn = fmaxf(m2, mx);
    const float corr = fexp2(m2 - mn);
    m2 = mn;

    float rs = 0.f;
#pragma unroll
    for (int kg = 0; kg < 4; ++kg) {
      union { bf16 hh[4]; uint2 v; } pk;
#pragma unroll
      for (int r = 0; r < 4; ++r) {
        const float p = fexp2(sc[kg][r] * c2 - mn);
        rs += p;
        pk.hh[r] = __float2bfloat16(p);
      }
      *(uint2*)(Pw + lo * 128 + ((((kg << 1) + (hi >> 1)) ^ (lo & 7)) << 4) +
                ((hi & 1) << 3)) = pk.v;
    }
    rs += __shfl_xor(rs, 16);
    rs += __shfl_xor(rs, 32);
    lsum = lsum * corr + rs;

    float corr_r[4];
#pragma unroll
    for (int r = 0; r < 4; ++r) corr_r[r] = __shfl(corr, hi * 4 + r);
#pragma unroll
    for (int dg = 0; dg < 8; ++dg)
#pragma unroll
      for (int r = 0; r < 4; ++r) oacc[dg][r] *= corr_r[r];

    asm volatile("s_waitcnt lgkmcnt(0)" ::: "memory");

    bf16x8 pf[2];
#pragma unroll
    for (int kc = 0; kc < 2; ++kc)
      pf[kc] = *(const bf16x8*)(Pw + lo * 128 + ((((kc << 2) + hi) ^ (lo & 7)) << 4));
#pragma unroll
    for (int dg = 0; dg < 8; ++dg) {
#pragma unroll
      for (int kc = 0; kc < 2; ++kc) {
        const int vrow = dg * 16 + lo;
        bf16x8 vf = *(const bf16x8*)(Vs + vrow * 128 + ((((kc << 2) + hi) ^ (vrow & 7)) << 4));
        oacc[dg] = MFMA16(pf[kc], vf, oacc[dg]);
      }
    }
    __syncthreads();
  }

  const float linv = 1.0f / lsum;
  float lr[4];
#pragma unroll
  for (int r = 0; r < 4; ++r) lr[r] = __shfl(linv, hi * 4 + r);
  bf16* op = out + (tok0 + q0 + w * 16 + hi * 4) * 2048 + h * 128 + lo;
#pragma unroll
  for (int dg = 0; dg < 8; ++dg)
#pragma unroll
    for (int r = 0; r < 4; ++r)
      op[(size_t)r * 2048 + dg * 16] = __float2bfloat16(oacc[dg][r] * lr[r]);
}

// ------------------------------------------------------------------ launch ----
extern "C" void kernel_launch(void* const* d_in, const int* in_sizes, int n_in,
                              void* d_out, int out_size, void* d_ws, size_t ws_size,
                              hipStream_t stream) {
  (void)in_sizes; (void)n_in; (void)out_size; (void)ws_size;
  const float* x  = (const float*)d_in[0];
  const float* s1 = (const float*)d_in[1];
  const float* Wq = (const float*)d_in[2];
  const float* bq = (const float*)d_in[3];
  const float* Wk = (const float*)d_in[4];
  const float* bk = (const float*)d_in[5];
  const float* Wv = (const float*)d_in[6];
  const float* bv = (const float*)d_in[7];
  const float* Wo = (const float*)d_in[8];
  const float* bo = (const float*)d_in[9];
  const float* W1 = (const float*)d_in[10];
  const float* b1 = (const float*)d_in[11];
  const float* W2 = (const float*)d_in[12];
  const float* b2 = (const float*)d_in[13];
  float* outp = (float*)d_out;

  char* ws = (char*)d_ws;
  bf16*  xn     = (bf16*)(ws + 0);           // 16.78 MB; dead after gemm8<0>
  bf16*  vtb    = (bf16*)(ws + 0);           // 4.19 MB, aliases dead xn
  bf16*  wcatT  = (bf16*)(ws + 16777216);    // [5120][2048] 20.97 MB; dead after gemm8<0>
  bf16*  attnb  = (bf16*)(ws + 16777216);    // [4096][2048] 16.78 MB, aliases dead wcatT
  float* bcat   = (float*)(ws + 37748736);   // 28 KB
  bf16*  wcat2T = (bf16*)(ws + 37781504);    // [2048][4096] 16.78 MB (Wo|W2 K-concat)
  bf16*  qkvb   = (bf16*)(ws + 54558720);    // [4096][3072] 25.17 MB
  bf16*  gbuf   = (bf16*)(ws + 79724544);    // [4096][2048] 16.78 MB

  const dim3 b32x8(32, 8);
  rmsnorm_cast_k<<<dim3(4096), dim3(256), 0, stream>>>(x, s1, xn);
  concat_bias_k<<<dim3(28), dim3(256), 0, stream>>>(bq, bk, bv, b1, bo, b2, bcat);
  transpose_cast_k<<<dim3(64, 64), b32x8, 0, stream>>>(Wq, wcatT, 2048, 2048, 0, 0);
  transpose_cast_k<<<dim3(16, 64), b32x8, 0, stream>>>(Wk, wcatT, 512, 2048, 2048, 0);
  transpose_cast_k<<<dim3(16, 64), b32x8, 0, stream>>>(Wv, wcatT, 512, 2048, 2560, 0);
  transpose_cast_k<<<dim3(64, 64), b32x8, 0, stream>>>(W1, wcatT, 2048, 2048, 3072, 0);
  transpose_cast_k<<<dim3(64, 64), b32x8, 0, stream>>>(Wo, wcat2T, 2048, 4096, 0, 0);
  transpose_cast_k<<<dim3(64, 64), b32x8, 0, stream>>>(W2, wcat2T, 2048, 4096, 0, 2048);
  // merged QKV + W1: [4096,2048] x [2048,5120], 256x320 tiles -> 256 blocks
  gemm8<8, 5, 2, 4, 0><<<dim3(16, 16), dim3(512), 147456, stream>>>(
      xn, xn, wcatT, bcat, (const float*)nullptr, (void*)qkvb, (void*)gbuf, 2048);
  transpose_v_k<<<dim3(32, 4, 16), b32x8, 0, stream>>>(qkvb, vtb);
  attn_fwd<<<dim3(16, 64), dim3(256), 0, stream>>>(qkvb, vtb, attnb);
  // out = x + attnb@Wo + gbuf@W2 + (bo+b2): [4096,4096]x[4096,2048], 256x128 tiles
  gemm8<4, 4, 4, 2, 1><<<dim3(16, 16), dim3(512), 98304, stream>>>(
      attnb, gbuf, wcat2T, bcat + 5120, x, (void*)outp, (void*)nullptr, 4096);
}